// Round 9
// baseline (340.095 us; speedup 1.0000x reference)
//
#include <hip/hip_runtime.h>
#include <hip/hip_bf16.h>

#define B_DIM 8192
#define IN_DIM 2048
#define OUT_DIM 2048
#define K2 (2 * IN_DIM)  // hi|lo concatenated K = 4096

typedef __attribute__((ext_vector_type(8))) __bf16 bf16x8;
typedef __attribute__((ext_vector_type(4))) float f32x4;

__device__ __forceinline__ unsigned short f32_to_bf16_rne(float f) {
    unsigned u = __float_as_uint(f);
    unsigned r = (u + 0x7FFFu + ((u >> 16) & 1u)) >> 16;
    return (unsigned short)r;
}
__device__ __forceinline__ float bf16u_to_f32(unsigned short h) {
    return __uint_as_float(((unsigned)h) << 16);
}

__device__ __forceinline__ void gload16(const void* g, void* l) {
    __builtin_amdgcn_global_load_lds(
        (const __attribute__((address_space(1))) void*)g,
        (__attribute__((address_space(3))) void*)l,
        16, 0, 0);
}

// ---------------- Stage 1: per-column partial sums (deterministic) -------------
__global__ void k_stats(const float* __restrict__ x, float* __restrict__ psum,
                        float* __restrict__ psq) {
    int col = blockIdx.x * 256 + threadIdx.x;
    int chunk = blockIdx.y;
    const float* p = x + (size_t)chunk * 256 * IN_DIM + col;
    float s = 0.f, s2 = 0.f;
#pragma unroll 8
    for (int r = 0; r < 256; ++r) {
        float v = p[(size_t)r * IN_DIM];
        s += v;
        s2 = fmaf(v, v, s2);
    }
    psum[chunk * IN_DIM + col] = s;
    psq[chunk * IN_DIM + col] = s2;
}

// ---------------- Stage 2: finalize mean/var -> scale/shift --------------------
__global__ void k_finalize(const float* __restrict__ psum, const float* __restrict__ psq,
                           const float* __restrict__ gamma, const float* __restrict__ beta,
                           float* __restrict__ scale, float* __restrict__ shift) {
    int c = blockIdx.x * 256 + threadIdx.x;
    float s = 0.f, s2 = 0.f;
#pragma unroll
    for (int ch = 0; ch < 32; ++ch) {
        s += psum[ch * IN_DIM + c];
        s2 += psq[ch * IN_DIM + c];
    }
    float mean = s * (1.0f / B_DIM);
    float var = fmaf(-mean, mean, s2 * (1.0f / B_DIM));
    float sc = gamma[c] * rsqrtf(var + 1e-5f);
    scale[c] = sc;
    shift[c] = fmaf(-mean, sc, beta[c]);
}

// ---------------- Stage 3: xn -> bf16 hi|lo concatenated A [8192][4096] --------
__global__ void k_prep_a(const float* __restrict__ x, const float* __restrict__ scale,
                         const float* __restrict__ shift, unsigned short* __restrict__ Acat) {
    int row = blockIdx.x;
    int c0 = threadIdx.x * 8;
    const float4* px = (const float4*)(x + (size_t)row * IN_DIM + c0);
    float4 v0 = px[0], v1 = px[1];
    const float4* ps = (const float4*)(scale + c0);
    float4 s0 = ps[0], s1 = ps[1];
    const float4* pb = (const float4*)(shift + c0);
    float4 b0 = pb[0], b1 = pb[1];
    float xs[8] = {v0.x, v0.y, v0.z, v0.w, v1.x, v1.y, v1.z, v1.w};
    float ss[8] = {s0.x, s0.y, s0.z, s0.w, s1.x, s1.y, s1.z, s1.w};
    float bb[8] = {b0.x, b0.y, b0.z, b0.w, b1.x, b1.y, b1.z, b1.w};
    union { unsigned short u[8]; uint4 v; } hi, lo;
#pragma unroll
    for (int j = 0; j < 8; ++j) {
        float xn = fmaf(xs[j], ss[j], bb[j]);
        unsigned short h = f32_to_bf16_rne(xn);
        float r = xn - bf16u_to_f32(h);
        hi.u[j] = h;
        lo.u[j] = f32_to_bf16_rne(r);
    }
    size_t base = (size_t)row * K2;
    *(uint4*)(Acat + base + c0) = hi.v;
    *(uint4*)(Acat + base + IN_DIM + c0) = lo.v;
}

// ---------------- Stage 4: weight sign -> bf16 +-1 [2048][2048] ----------------
__global__ void k_prep_b(const float* __restrict__ w, unsigned short* __restrict__ Bsgn) {
    int row = blockIdx.x;
    int c0 = threadIdx.x * 8;
    const float4* pw = (const float4*)(w + (size_t)row * IN_DIM + c0);
    float4 v0 = pw[0], v1 = pw[1];
    float wv[8] = {v0.x, v0.y, v0.z, v0.w, v1.x, v1.y, v1.z, v1.w};
    union { unsigned short u[8]; uint4 v; } sb;
#pragma unroll
    for (int j = 0; j < 8; ++j) sb.u[j] = (wv[j] >= 0.0f) ? 0x3F80u : 0xBF80u;
    *(uint4*)(Bsgn + (size_t)row * IN_DIM + c0) = sb.v;
}

// ---------------- Stage 5: 256x256 tile, hi/lo PAIRED on shared B --------------
// R5 skeleton (reg-prefetched fragments, 16-MFMA phases) + B staged & read ONCE
// per k-tile, reused by both A-halves (bp regs persist; zero new live state).
// A-hi/A-lo double-buffered in LDS (Ab0/Ab1); B double-buffered (Bb0/Bb1).
// Per pair: 8 phases, 2 barriers, vmcnt(4) then vmcnt(0).
#define BM 256
#define BN 256
#define BK 64
#define NWG ((B_DIM / BM) * (OUT_DIM / BN))  // 256
#define NKT (IN_DIM / BK)                    // 32 k-tiles (pairs)
// LDS map (elems): Ab0 0, Ab1 16384, Bb0 32768, Bb1 49152 (128 KiB)

#define MEMF() asm volatile("" ::: "memory")
#define BARRIER() do { MEMF(); __builtin_amdgcn_s_barrier(); MEMF(); } while (0)
#define WAITVM(N) asm volatile("s_waitcnt vmcnt(" #N ")" ::: "memory")
#define WAITLGKM0() asm volatile("s_waitcnt lgkmcnt(0)" ::: "memory")

__global__ __launch_bounds__(512, 2) void k_gemm(const unsigned short* __restrict__ A,
                                                 const unsigned short* __restrict__ Bsgn,
                                                 float* __restrict__ out) {
    __shared__ __align__(16) unsigned short sh[65536];  // 128 KiB

    // T1: XCD-aware swizzle (256 % 8 == 0 -> bijective)
    int bid = blockIdx.x;
    int swz = (bid & 7) * (NWG / 8) + (bid >> 3);
    int mt = swz >> 3, nt = swz & 7;
    int m0 = mt * BM, n0 = nt * BN;

    int t = threadIdx.x;
    int lane = t & 63, w = t >> 6;
    int wm = w >> 1, wn = w & 1;         // 4m x 2n waves; per-wave out 64 x 128
    int lrow = lane & 15, lg = lane >> 4;
    int lq = lane >> 3, lslot = lane & 7;
    int tsl = lslot ^ lq;                // pre-swizzled source slot (row&7 == lq)

    int sl0 = (lg ^ (lane & 7)) << 3;          // ks=0 read slot offset (elems)
    int sl1 = ((lg + 4) ^ (lane & 7)) << 3;    // ks=1

    int aRd = (wm * 64 + lrow) * BK;
    int bRd = (wn * 128 + lrow) * BK;

    // A staging: wave stages its own 64 rows; half h -> Ab[h]; piece j (4/wave)
    auto stageA = [&](int h, int j, int kt) {
        int q = wn * 4 + j;
        const unsigned short* src =
            A + (size_t)(m0 + wm * 64 + q * 8 + lq) * K2 + h * IN_DIM + kt * BK + tsl * 8;
        gload16(src, (unsigned short*)sh + h * 16384 + wm * 4096 + q * 512 + lane * 8);
    };
    // B staging: chunk cb=2wn+i, piece q=wm*2+j
    auto stageB = [&](unsigned short* bbuf, int i, int j, int kt) {
        int cb = 2 * wn + i;
        int q = wm * 2 + j;
        const unsigned short* src =
            Bsgn + (size_t)(n0 + cb * 64 + q * 8 + lq) * IN_DIM + kt * BK + tsl * 8;
        gload16(src, bbuf + cb * 4096 + q * 512 + lane * 8);
    };

    f32x4 acc[4][8] = {};

#define LDAF(h, m, sl) (*(const bf16x8*)&sh[(h) * 16384 + aRd + (m) * 1024 + (sl)])
#define LDB(buf, n, sl) (*(const bf16x8*)&(buf)[bRd + (n) * 1024 + (sl)])
#define MFMA_PAIR(NP, BP)                                                          \
    do {                                                                           \
        __builtin_amdgcn_s_setprio(1);                                             \
        _Pragma("unroll") for (int ks = 0; ks < 2; ++ks)                           \
            _Pragma("unroll") for (int m = 0; m < 4; ++m)                          \
                _Pragma("unroll") for (int i = 0; i < 2; ++i)                      \
                    acc[m][(NP) + i] = __builtin_amdgcn_mfma_f32_16x16x32_bf16(    \
                        af[m][ks], BP[i][ks], acc[m][(NP) + i], 0, 0, 0);          \
        __builtin_amdgcn_s_setprio(0);                                             \
    } while (0)

    bf16x8 af[4][2];                     // current sub-tile's A fragments
    bf16x8 bpA[2][2], bpB[2][2], bpC[2][2], bpD[2][2];  // persist across the pair

    // Prologue: stage B(0)->Bb0, A(0,hi)->Ab0; drain; read af + bpA
    {
        unsigned short* Bb0 = (unsigned short*)sh + 32768;
        stageB(Bb0, 0, 0, 0); stageB(Bb0, 0, 1, 0); stageB(Bb0, 1, 0, 0); stageB(Bb0, 1, 1, 0);
        stageA(0, 0, 0); stageA(0, 1, 0); stageA(0, 2, 0); stageA(0, 3, 0);
        WAITVM(0);
        BARRIER();
#pragma unroll
        for (int m = 0; m < 4; ++m) { af[m][0] = LDAF(0, m, sl0); af[m][1] = LDAF(0, m, sl1); }
#pragma unroll
        for (int i = 0; i < 2; ++i) { bpA[i][0] = LDB(Bb0, i, sl0); bpA[i][1] = LDB(Bb0, i, sl1); }
    }

#pragma unroll 2
    for (int p = 0; p < NKT; ++p) {
        const unsigned short* Bcur = sh + 32768 + (p & 1) * 16384;
        unsigned short* Bnxt = (unsigned short*)sh + 32768 + ((p + 1) & 1) * 16384;
        bool pf = (p < NKT - 1);
        int kn = p + 1;

        // ======== sub0: A-hi (af preloaded at prev pair's tail) ========
        // ph0: stage A-lo j0,j1 -> Ab1; read bpB; MFMA n{0,1}
        stageA(1, 0, p); stageA(1, 1, p);
#pragma unroll
        for (int i = 0; i < 2; ++i) { bpB[i][0] = LDB(Bcur, 2 + i, sl0); bpB[i][1] = LDB(Bcur, 2 + i, sl1); }
        MFMA_PAIR(0, bpA);

        // ph1: stage A-lo j2,j3; read bpC; MFMA n{2,3}
        stageA(1, 2, p); stageA(1, 3, p);
#pragma unroll
        for (int i = 0; i < 2; ++i) { bpC[i][0] = LDB(Bcur, 4 + i, sl0); bpC[i][1] = LDB(Bcur, 4 + i, sl1); }
        MFMA_PAIR(2, bpB);

        // ph2: stage B(p+1) -> Bnxt; read bpD; MFMA n{4,5}
        if (pf) { stageB(Bnxt, 0, 0, kn); stageB(Bnxt, 0, 1, kn);
                  stageB(Bnxt, 1, 0, kn); stageB(Bnxt, 1, 1, kn); }
#pragma unroll
        for (int i = 0; i < 2; ++i) { bpD[i][0] = LDB(Bcur, 6 + i, sl0); bpD[i][1] = LDB(Bcur, 6 + i, sl1); }
        MFMA_PAIR(4, bpC);

        // ph3: drain A-lo (leave B(p+1) in flight); barrier; MFMA n{6,7}; read af<-Ab1
        if (pf) { WAITVM(4); } else { WAITVM(0); }
        WAITLGKM0();
        BARRIER();
        MFMA_PAIR(6, bpD);
#pragma unroll
        for (int m = 0; m < 4; ++m) { af[m][0] = LDAF(1, m, sl0); af[m][1] = LDAF(1, m, sl1); }

        // ======== sub1: A-lo (bp regs REUSED -- no LDS B reads) ========
        // ph0: stage A(p+1,hi) j0,j1 -> Ab0; MFMA n{0,1}
        if (pf) { stageA(0, 0, kn); stageA(0, 1, kn); }
        MFMA_PAIR(0, bpA);

        // ph1: stage A(p+1,hi) j2,j3; MFMA n{2,3}
        if (pf) { stageA(0, 2, kn); stageA(0, 3, kn); }
        MFMA_PAIR(2, bpB);

        // ph2: MFMA n{4,5}
        MFMA_PAIR(4, bpC);

        // ph3: drain all; barrier; MFMA n{6,7}; read next af<-Ab0, bpA<-Bnxt
        WAITVM(0);
        WAITLGKM0();
        BARRIER();
        MFMA_PAIR(6, bpD);
        if (pf) {
#pragma unroll
            for (int m = 0; m < 4; ++m) { af[m][0] = LDAF(0, m, sl0); af[m][1] = LDAF(0, m, sl1); }
#pragma unroll
            for (int i = 0; i < 2; ++i) { bpA[i][0] = LDB(Bnxt, i, sl0); bpA[i][1] = LDB(Bnxt, i, sl1); }
        }
    }

    // Epilogue: C/D map col=lane&15, row=(lane>>4)*4+reg; fused hardtanh
#pragma unroll
    for (int m = 0; m < 4; ++m) {
#pragma unroll
        for (int n = 0; n < 8; ++n) {
#pragma unroll
            for (int r = 0; r < 4; ++r) {
                int row = m0 + wm * 64 + m * 16 + lg * 4 + r;
                int col = n0 + wn * 128 + n * 16 + lrow;
                float v = acc[m][n][r];
                v = fminf(fmaxf(v, -1.0f), 1.0f);
                out[(size_t)row * OUT_DIM + col] = v;
            }
        }
    }
}

extern "C" void kernel_launch(void* const* d_in, const int* in_sizes, int n_in,
                              void* d_out, int out_size, void* d_ws, size_t ws_size,
                              hipStream_t stream) {
    const float* x = (const float*)d_in[0];
    const float* w = (const float*)d_in[1];
    const float* gamma = (const float*)d_in[2];
    const float* beta = (const float*)d_in[3];
    float* out = (float*)d_out;

    float* wsf = (float*)d_ws;
    float* psum = wsf;                                   // 32*2048 f32
    float* psq = wsf + 32 * IN_DIM;                      // 32*2048 f32
    float* scale = wsf + 64 * IN_DIM;                    // 2048 f32
    float* shift = wsf + 65 * IN_DIM;                    // 2048 f32
    unsigned short* Bsgn = (unsigned short*)(wsf + 66 * IN_DIM);  // 8 MB
    unsigned short* Acat = Bsgn + (size_t)OUT_DIM * IN_DIM;       // 64 MB

    k_stats<<<dim3(8, 32), 256, 0, stream>>>(x, psum, psq);
    k_finalize<<<8, 256, 0, stream>>>(psum, psq, gamma, beta, scale, shift);
    k_prep_a<<<B_DIM, 256, 0, stream>>>(x, scale, shift, Acat);
    k_prep_b<<<OUT_DIM, 256, 0, stream>>>(w, Bsgn);
    k_gemm<<<NWG, 512, 0, stream>>>(Acat, Bsgn, out);
}

// Round 10
// 174.332 us; speedup vs baseline: 1.9509x; 1.9509x over previous
//
#include <hip/hip_runtime.h>
#include <hip/hip_bf16.h>

#define B_DIM 8192
#define IN_DIM 2048
#define OUT_DIM 2048
#define K2 (2 * IN_DIM)  // hi|lo concatenated K = 4096

typedef __attribute__((ext_vector_type(8))) __bf16 bf16x8;
typedef __attribute__((ext_vector_type(4))) float f32x4;
typedef __attribute__((ext_vector_type(16))) float f32x16;

__device__ __forceinline__ unsigned short f32_to_bf16_rne(float f) {
    unsigned u = __float_as_uint(f);
    unsigned r = (u + 0x7FFFu + ((u >> 16) & 1u)) >> 16;
    return (unsigned short)r;
}
__device__ __forceinline__ float bf16u_to_f32(unsigned short h) {
    return __uint_as_float(((unsigned)h) << 16);
}

__device__ __forceinline__ void gload16(const void* g, void* l) {
    __builtin_amdgcn_global_load_lds(
        (const __attribute__((address_space(1))) void*)g,
        (__attribute__((address_space(3))) void*)l,
        16, 0, 0);
}

// ---------------- Stage 1: per-column partial sums (deterministic) -------------
__global__ void k_stats(const float* __restrict__ x, float* __restrict__ psum,
                        float* __restrict__ psq) {
    int col = blockIdx.x * 256 + threadIdx.x;
    int chunk = blockIdx.y;
    const float* p = x + (size_t)chunk * 256 * IN_DIM + col;
    float s = 0.f, s2 = 0.f;
#pragma unroll 8
    for (int r = 0; r < 256; ++r) {
        float v = p[(size_t)r * IN_DIM];
        s += v;
        s2 = fmaf(v, v, s2);
    }
    psum[chunk * IN_DIM + col] = s;
    psq[chunk * IN_DIM + col] = s2;
}

// ---------------- Stage 2: finalize mean/var -> scale/shift --------------------
__global__ void k_finalize(const float* __restrict__ psum, const float* __restrict__ psq,
                           const float* __restrict__ gamma, const float* __restrict__ beta,
                           float* __restrict__ scale, float* __restrict__ shift) {
    int c = blockIdx.x * 256 + threadIdx.x;
    float s = 0.f, s2 = 0.f;
#pragma unroll
    for (int ch = 0; ch < 32; ++ch) {
        s += psum[ch * IN_DIM + c];
        s2 += psq[ch * IN_DIM + c];
    }
    float mean = s * (1.0f / B_DIM);
    float var = fmaf(-mean, mean, s2 * (1.0f / B_DIM));
    float sc = gamma[c] * rsqrtf(var + 1e-5f);
    scale[c] = sc;
    shift[c] = fmaf(-mean, sc, beta[c]);
}

// ---------------- Stage 3: xn -> bf16 hi|lo concatenated A [8192][4096] --------
__global__ void k_prep_a(const float* __restrict__ x, const float* __restrict__ scale,
                         const float* __restrict__ shift, unsigned short* __restrict__ Acat) {
    int row = blockIdx.x;
    int c0 = threadIdx.x * 8;
    const float4* px = (const float4*)(x + (size_t)row * IN_DIM + c0);
    float4 v0 = px[0], v1 = px[1];
    const float4* ps = (const float4*)(scale + c0);
    float4 s0 = ps[0], s1 = ps[1];
    const float4* pb = (const float4*)(shift + c0);
    float4 b0 = pb[0], b1 = pb[1];
    float xs[8] = {v0.x, v0.y, v0.z, v0.w, v1.x, v1.y, v1.z, v1.w};
    float ss[8] = {s0.x, s0.y, s0.z, s0.w, s1.x, s1.y, s1.z, s1.w};
    float bb[8] = {b0.x, b0.y, b0.z, b0.w, b1.x, b1.y, b1.z, b1.w};
    union { unsigned short u[8]; uint4 v; } hi, lo;
#pragma unroll
    for (int j = 0; j < 8; ++j) {
        float xn = fmaf(xs[j], ss[j], bb[j]);
        unsigned short h = f32_to_bf16_rne(xn);
        float r = xn - bf16u_to_f32(h);
        hi.u[j] = h;
        lo.u[j] = f32_to_bf16_rne(r);
    }
    size_t base = (size_t)row * K2;
    *(uint4*)(Acat + base + c0) = hi.v;
    *(uint4*)(Acat + base + IN_DIM + c0) = lo.v;
}

// ---------------- Stage 4: weight sign -> bf16 +-1 [2048][2048] ----------------
__global__ void k_prep_b(const float* __restrict__ w, unsigned short* __restrict__ Bsgn) {
    int row = blockIdx.x;
    int c0 = threadIdx.x * 8;
    const float4* pw = (const float4*)(w + (size_t)row * IN_DIM + c0);
    float4 v0 = pw[0], v1 = pw[1];
    float wv[8] = {v0.x, v0.y, v0.z, v0.w, v1.x, v1.y, v1.z, v1.w};
    union { unsigned short u[8]; uint4 v; } sb;
#pragma unroll
    for (int j = 0; j < 8; ++j) sb.u[j] = (wv[j] >= 0.0f) ? 0x3F80u : 0xBF80u;
    *(uint4*)(Bsgn + (size_t)row * IN_DIM + c0) = sb.v;
}

// ---------------- Stage 5: R5 skeleton + 32x32x16 MFMA -------------------------
// Same staging/waits/barriers/lifetimes as the verified 114us kernel; only the
// MFMA shape changes (8.07cy/32kFLOP vs 4.85cy/16kFLOP -> -19% matrix-pipe floor).
// Per wave: out 64x128 = 2rb x 4cb tiles of 32x32; acc[2][4] f32x16 (128 regs).
// A frag: lane holds A[row=rb*32+(l&31)][k=ks*16+(l>>5)*8+j]; B symmetric.
#define BM 256
#define BN 256
#define BK 64
#define NWG ((B_DIM / BM) * (OUT_DIM / BN))  // 256
#define NKT (K2 / BK)                        // 64
#define TILE_E (BM * BK)                     // 16384 elems = 32 KB

#define MEMF() asm volatile("" ::: "memory")
#define BARRIER() do { MEMF(); __builtin_amdgcn_s_barrier(); MEMF(); } while (0)
#define WAITVM(N) asm volatile("s_waitcnt vmcnt(" #N ")" ::: "memory")
#define WAITLGKM0() asm volatile("s_waitcnt lgkmcnt(0)" ::: "memory")

__global__ __launch_bounds__(512, 2) void k_gemm(const unsigned short* __restrict__ A,
                                                 const unsigned short* __restrict__ Bsgn,
                                                 float* __restrict__ out) {
    __shared__ __align__(16) unsigned short sh[4 * TILE_E];  // 128 KiB

    // T1: XCD-aware swizzle (256 % 8 == 0 -> bijective)
    int bid = blockIdx.x;
    int swz = (bid & 7) * (NWG / 8) + (bid >> 3);
    int mt = swz >> 3, nt = swz & 7;
    int m0 = mt * BM, n0 = nt * BN;

    int t = threadIdx.x;
    int lane = t & 63, w = t >> 6;
    int wm = w >> 1, wn = w & 1;         // 4m x 2n waves; per-wave out 64 x 128
    int lr32 = lane & 31, hk = lane >> 5;
    int lq = lane >> 3, lslot = lane & 7;
    int tsl = lslot ^ lq;                // pre-swizzled source slot (row&7 == lq)

    // 16B-slot offsets (elems) for k-sub ks: slot = ks*2 + hk, XOR row&7 (== lane&7)
    const int sk[4] = {((0 + hk) ^ (lane & 7)) << 3, ((2 + hk) ^ (lane & 7)) << 3,
                       ((4 + hk) ^ (lane & 7)) << 3, ((6 + hk) ^ (lane & 7)) << 3};

    int aRdB = (wm * 64 + lr32) * BK;
    int bRdB = (wn * 128 + lr32) * BK;

    // A staging: wave pair (wm) stages its 64 rows; piece j (4 per wave)
    auto stageA = [&](unsigned short* abuf, int j, int kt) {
        int q = wn * 4 + j;
        const unsigned short* src =
            A + (size_t)(m0 + wm * 64 + q * 8 + lq) * K2 + kt * BK + tsl * 8;
        gload16(src, abuf + wm * (64 * BK) + q * 512 + lane * 8);
    };
    // B staging: chunk cb64=2wn+i (64 cols), piece q=wm*2+j
    auto stageB = [&](unsigned short* bbuf, int i, int j, int kt) {
        int cb = 2 * wn + i;
        int q = wm * 2 + j;
        const unsigned short* src =
            Bsgn + (size_t)(n0 + cb * 64 + q * 8 + lq) * IN_DIM +
            ((kt * BK) & (IN_DIM - 1)) + tsl * 8;
        gload16(src, bbuf + cb * (64 * BK) + q * 512 + lane * 8);
    };

    f32x16 acc[2][4] = {};

#define LDA32(buf, rb, ks) (*(const bf16x8*)&(buf)[aRdB + (rb) * (32 * BK) + sk[ks]])
#define LDB32(buf, cb, ks) (*(const bf16x8*)&(buf)[bRdB + (cb) * (32 * BK) + sk[ks]])
// 8 MFMAs for one 32-col block CB: ks outer, rb inner (2 indep acc chains)
#define MFMA_CB(CB, BP)                                                            \
    do {                                                                           \
        __builtin_amdgcn_s_setprio(1);                                             \
        _Pragma("unroll") for (int ks = 0; ks < 4; ++ks)                           \
            _Pragma("unroll") for (int rb = 0; rb < 2; ++rb)                       \
                acc[rb][CB] = __builtin_amdgcn_mfma_f32_32x32x16_bf16(             \
                    af[rb][ks], BP[ks], acc[rb][CB], 0, 0, 0);                     \
        __builtin_amdgcn_s_setprio(0);                                             \
    } while (0)

    bf16x8 af[2][4];                       // current tile's A frags [rb][ks]
    bf16x8 bpA[4], bpB[4], bpC[4], bpD[4]; // B frag groups cb0..cb3 [ks]

    // Prologue: stage tile0 A+B chunk0 fully + B chunk1 late pair, drain as R5
    {
        unsigned short* A0b = (unsigned short*)sh;
        unsigned short* B0b = A0b + TILE_E;
        stageA(A0b, 0, 0); stageA(A0b, 1, 0); stageB(B0b, 0, 0, 0);
        stageB(B0b, 0, 1, 0); stageA(A0b, 2, 0); stageA(A0b, 3, 0);
        WAITVM(0);
        BARRIER();
        stageB(B0b, 1, 0, 0); stageB(B0b, 1, 1, 0);
#pragma unroll
        for (int rb = 0; rb < 2; ++rb)
#pragma unroll
            for (int ks = 0; ks < 4; ++ks) af[rb][ks] = LDA32(A0b, rb, ks);
#pragma unroll
        for (int ks = 0; ks < 4; ++ks) bpA[ks] = LDB32(B0b, 0, ks);
    }

#pragma unroll 2
    for (int T = 0; T < NKT; ++T) {
        const unsigned short* Ab = sh + (T & 1) * (2 * TILE_E);
        const unsigned short* Bb = Ab + TILE_E;
        unsigned short* An = (unsigned short*)sh + ((T & 1) ^ 1) * (2 * TILE_E);
        unsigned short* Bn = An + TILE_E;
        bool pf = (T < NKT - 1);
        int kn = T + 1;

        // ---- ph0: MFMA cb0; prefetch bpB (cb1, chunk0); stage A0,A1,B0a ----
        if (pf) { stageA(An, 0, kn); stageA(An, 1, kn); stageB(Bn, 0, 0, kn); }
#pragma unroll
        for (int ks = 0; ks < 4; ++ks) bpB[ks] = LDB32(Bb, 1, ks);
        MFMA_CB(0, bpA);

        // ---- ph1: drain this tile's B chunk1, barrier; MFMA cb1 ----
        if (pf) { WAITVM(3); } else { WAITVM(0); }
        WAITLGKM0();
        BARRIER();
        if (pf) { stageB(Bn, 0, 1, kn); stageA(An, 2, kn); stageA(An, 3, kn); }
#pragma unroll
        for (int ks = 0; ks < 4; ++ks) bpC[ks] = LDB32(Bb, 2, ks);
        MFMA_CB(1, bpB);

        // ---- ph2: prefetch bpD (cb3); MFMA cb2 (no barrier) ----
#pragma unroll
        for (int ks = 0; ks < 4; ++ks) bpD[ks] = LDB32(Bb, 3, ks);
        MFMA_CB(2, bpC);

        // ---- ph3: drain next tile's A+B chunk0, barrier; MFMA cb3;
        //      read next tile's af + bpA; issue next tile's B chunk1 pair ----
        WAITVM(0);
        WAITLGKM0();
        BARRIER();
        if (pf) { stageB(Bn, 1, 0, kn); stageB(Bn, 1, 1, kn); }
        MFMA_CB(3, bpD);
        if (pf) {
#pragma unroll
            for (int rb = 0; rb < 2; ++rb)
#pragma unroll
                for (int ks = 0; ks < 4; ++ks) af[rb][ks] = LDA32(An, rb, ks);
#pragma unroll
            for (int ks = 0; ks < 4; ++ks) bpA[ks] = LDB32(Bn, 0, ks);
        }
    }

    // Epilogue: 32x32 C/D map col=lane&31, row=(reg&3)+8*(reg>>2)+4*(lane>>5)
#pragma unroll
    for (int rb = 0; rb < 2; ++rb) {
#pragma unroll
        for (int cb = 0; cb < 4; ++cb) {
#pragma unroll
            for (int r = 0; r < 16; ++r) {
                int row = m0 + wm * 64 + rb * 32 + hk * 4 + (r & 3) + 8 * (r >> 2);
                int col = n0 + wn * 128 + cb * 32 + lr32;
                float v = acc[rb][cb][r];
                v = fminf(fmaxf(v, -1.0f), 1.0f);
                out[(size_t)row * OUT_DIM + col] = v;
            }
        }
    }
}

extern "C" void kernel_launch(void* const* d_in, const int* in_sizes, int n_in,
                              void* d_out, int out_size, void* d_ws, size_t ws_size,
                              hipStream_t stream) {
    const float* x = (const float*)d_in[0];
    const float* w = (const float*)d_in[1];
    const float* gamma = (const float*)d_in[2];
    const float* beta = (const float*)d_in[3];
    float* out = (float*)d_out;

    float* wsf = (float*)d_ws;
    float* psum = wsf;                                   // 32*2048 f32
    float* psq = wsf + 32 * IN_DIM;                      // 32*2048 f32
    float* scale = wsf + 64 * IN_DIM;                    // 2048 f32
    float* shift = wsf + 65 * IN_DIM;                    // 2048 f32
    unsigned short* Bsgn = (unsigned short*)(wsf + 66 * IN_DIM);  // 8 MB
    unsigned short* Acat = Bsgn + (size_t)OUT_DIM * IN_DIM;       // 64 MB

    k_stats<<<dim3(8, 32), 256, 0, stream>>>(x, psum, psq);
    k_finalize<<<8, 256, 0, stream>>>(psum, psq, gamma, beta, scale, shift);
    k_prep_a<<<B_DIM, 256, 0, stream>>>(x, scale, shift, Acat);
    k_prep_b<<<OUT_DIM, 256, 0, stream>>>(w, Bsgn);
    k_gemm<<<NWG, 512, 0, stream>>>(Acat, Bsgn, out);
}

// Round 11
// 166.295 us; speedup vs baseline: 2.0451x; 1.0483x over previous
//
#include <hip/hip_runtime.h>
#include <hip/hip_bf16.h>

#define B_DIM 8192
#define IN_DIM 2048
#define OUT_DIM 2048
#define K2 (2 * IN_DIM)  // hi|lo concatenated K = 4096

typedef __attribute__((ext_vector_type(8))) __bf16 bf16x8;
typedef __attribute__((ext_vector_type(4))) float f32x4;

__device__ __forceinline__ unsigned short f32_to_bf16_rne(float f) {
    unsigned u = __float_as_uint(f);
    unsigned r = (u + 0x7FFFu + ((u >> 16) & 1u)) >> 16;
    return (unsigned short)r;
}
__device__ __forceinline__ float bf16u_to_f32(unsigned short h) {
    return __uint_as_float(((unsigned)h) << 16);
}

__device__ __forceinline__ void gload16(const void* g, void* l) {
    __builtin_amdgcn_global_load_lds(
        (const __attribute__((address_space(1))) void*)g,
        (__attribute__((address_space(3))) void*)l,
        16, 0, 0);
}

// ---------------- Stage 1: per-column partial sums (deterministic) -------------
__global__ void k_stats(const float* __restrict__ x, float* __restrict__ psum,
                        float* __restrict__ psq) {
    int col = blockIdx.x * 256 + threadIdx.x;
    int chunk = blockIdx.y;
    const float* p = x + (size_t)chunk * 256 * IN_DIM + col;
    float s = 0.f, s2 = 0.f;
#pragma unroll 8
    for (int r = 0; r < 256; ++r) {
        float v = p[(size_t)r * IN_DIM];
        s += v;
        s2 = fmaf(v, v, s2);
    }
    psum[chunk * IN_DIM + col] = s;
    psq[chunk * IN_DIM + col] = s2;
}

// ---------------- Stage 2: finalize mean/var -> scale/shift --------------------
__global__ void k_finalize(const float* __restrict__ psum, const float* __restrict__ psq,
                           const float* __restrict__ gamma, const float* __restrict__ beta,
                           float* __restrict__ scale, float* __restrict__ shift) {
    int c = blockIdx.x * 256 + threadIdx.x;
    float s = 0.f, s2 = 0.f;
#pragma unroll
    for (int ch = 0; ch < 32; ++ch) {
        s += psum[ch * IN_DIM + c];
        s2 += psq[ch * IN_DIM + c];
    }
    float mean = s * (1.0f / B_DIM);
    float var = fmaf(-mean, mean, s2 * (1.0f / B_DIM));
    float sc = gamma[c] * rsqrtf(var + 1e-5f);
    scale[c] = sc;
    shift[c] = fmaf(-mean, sc, beta[c]);
}

// ---------------- Stage 3: xn -> bf16 hi|lo concatenated A [8192][4096] --------
__global__ void k_prep_a(const float* __restrict__ x, const float* __restrict__ scale,
                         const float* __restrict__ shift, unsigned short* __restrict__ Acat) {
    int row = blockIdx.x;
    int c0 = threadIdx.x * 8;
    const float4* px = (const float4*)(x + (size_t)row * IN_DIM + c0);
    float4 v0 = px[0], v1 = px[1];
    const float4* ps = (const float4*)(scale + c0);
    float4 s0 = ps[0], s1 = ps[1];
    const float4* pb = (const float4*)(shift + c0);
    float4 b0 = pb[0], b1 = pb[1];
    float xs[8] = {v0.x, v0.y, v0.z, v0.w, v1.x, v1.y, v1.z, v1.w};
    float ss[8] = {s0.x, s0.y, s0.z, s0.w, s1.x, s1.y, s1.z, s1.w};
    float bb[8] = {b0.x, b0.y, b0.z, b0.w, b1.x, b1.y, b1.z, b1.w};
    union { unsigned short u[8]; uint4 v; } hi, lo;
#pragma unroll
    for (int j = 0; j < 8; ++j) {
        float xn = fmaf(xs[j], ss[j], bb[j]);
        unsigned short h = f32_to_bf16_rne(xn);
        float r = xn - bf16u_to_f32(h);
        hi.u[j] = h;
        lo.u[j] = f32_to_bf16_rne(r);
    }
    size_t base = (size_t)row * K2;
    *(uint4*)(Acat + base + c0) = hi.v;
    *(uint4*)(Acat + base + IN_DIM + c0) = lo.v;
}

// ---------------- Stage 4: weight sign -> bf16 +-1 [2048][2048] ----------------
__global__ void k_prep_b(const float* __restrict__ w, unsigned short* __restrict__ Bsgn) {
    int row = blockIdx.x;
    int c0 = threadIdx.x * 8;
    const float4* pw = (const float4*)(w + (size_t)row * IN_DIM + c0);
    float4 v0 = pw[0], v1 = pw[1];
    float wv[8] = {v0.x, v0.y, v0.z, v0.w, v1.x, v1.y, v1.z, v1.w};
    union { unsigned short u[8]; uint4 v; } sb;
#pragma unroll
    for (int j = 0; j < 8; ++j) sb.u[j] = (wv[j] >= 0.0f) ? 0x3F80u : 0xBF80u;
    *(uint4*)(Bsgn + (size_t)row * IN_DIM + c0) = sb.v;
}

// ---------------- Stage 5: m201-style 8-wave 2Mx4N 4-phase GEMM ----------------
// Per-wave out 128x64: every wave reads exactly ONE A-half and ONE B-half.
// Phase = {ds_reads; stages; barrier; setprio1; 16 MFMA; setprio0; barrier}.
// Stages compressed to ph0-2 so the single vmcnt(0)@ph3 drains loads >=1.5
// phases old (near-free). B frags (8 reads) land at ph0; af 4 reads/phase.
#define BM 256
#define BN 256
#define BK 64
#define NWG ((B_DIM / BM) * (OUT_DIM / BN))  // 256
#define NKT (K2 / BK)                        // 64
#define TILE_E (BM * BK)                     // 16384 elems = 32 KB

#define MEMF() asm volatile("" ::: "memory")
#define BARRIER() do { MEMF(); __builtin_amdgcn_s_barrier(); MEMF(); } while (0)
#define WAITVM(N) asm volatile("s_waitcnt vmcnt(" #N ")" ::: "memory")

__global__ __launch_bounds__(512, 2) void k_gemm(const unsigned short* __restrict__ A,
                                                 const unsigned short* __restrict__ Bsgn,
                                                 float* __restrict__ out) {
    __shared__ __align__(16) unsigned short sh[4 * TILE_E];  // 128 KiB

    // T1: XCD-aware swizzle (256 % 8 == 0 -> bijective)
    int bid = blockIdx.x;
    int swz = (bid & 7) * (NWG / 8) + (bid >> 3);
    int mt = swz >> 3, nt = swz & 7;
    int m0 = mt * BM, n0 = nt * BN;

    int t = threadIdx.x;
    int lane = t & 63, w = t >> 6;
    int wm = w >> 2, wn = w & 3;         // 2M x 4N waves; per-wave out 128 x 64
    int lrow = lane & 15, lg = lane >> 4;

    int sl0 = (lg ^ (lane & 7)) << 3;          // ks=0 read slot offset (elems)
    int sl1 = ((lg + 4) ^ (lane & 7)) << 3;    // ks=1

    int aRd = (wm * 128 + lrow) * BK;
    int bRd = (wn * 64 + lrow) * BK;

    // Block-uniform staging: thread t covers row trow of a 64-row chunk,
    // pre-swizzled source slot (rule 21: linear LDS dest + swizzled source)
    int trow = t >> 3;
    int tslot = (t & 7) ^ (trow & 7);

    auto stageA = [&](unsigned short* abuf, int sub, int kt) {  // sub: 64-row chunk 0..3
        const unsigned short* src =
            A + (size_t)(m0 + sub * 64 + trow) * K2 + kt * BK + tslot * 8;
        gload16(src, abuf + sub * (64 * BK) + t * 8);
    };
    auto stageB = [&](unsigned short* bbuf, int sub, int kt) {
        const unsigned short* src =
            Bsgn + (size_t)(n0 + sub * 64 + trow) * IN_DIM +
            ((kt * BK) & (IN_DIM - 1)) + tslot * 8;
        gload16(src, bbuf + sub * (64 * BK) + t * 8);
    };

    f32x4 acc[8][4] = {};

#define LDA(buf, m, sl) (*(const bf16x8*)&(buf)[aRd + (m) * (16 * BK) + (sl)])
#define LDB(buf, n, sl) (*(const bf16x8*)&(buf)[bRd + (n) * (16 * BK) + (sl)])
// One phase's MFMA cluster: m-quadrant {2Q, 2Q+1} x n{0..3} x ks{0,1}
#define MFMA_Q(Q)                                                                  \
    do {                                                                           \
        __builtin_amdgcn_s_setprio(1);                                             \
        _Pragma("unroll") for (int ks = 0; ks < 2; ++ks)                           \
            _Pragma("unroll") for (int n = 0; n < 4; ++n)                          \
                _Pragma("unroll") for (int i = 0; i < 2; ++i)                      \
                    acc[2 * (Q) + i][n] = __builtin_amdgcn_mfma_f32_16x16x32_bf16( \
                        af[i][ks], bp[n][ks], acc[2 * (Q) + i][n], 0, 0, 0);       \
        __builtin_amdgcn_s_setprio(0);                                             \
    } while (0)

    // Prologue: stage tile 0 fully; drain; barrier.
    {
        unsigned short* A0 = (unsigned short*)sh;
        unsigned short* B0 = A0 + TILE_E;
        stageB(B0, 0, 0); stageB(B0, 1, 0); stageB(B0, 2, 0); stageB(B0, 3, 0);
        stageA(A0, 0, 0); stageA(A0, 1, 0); stageA(A0, 2, 0); stageA(A0, 3, 0);
        WAITVM(0);
        BARRIER();
    }

#pragma unroll 2
    for (int T = 0; T < NKT; ++T) {
        const unsigned short* Ab = sh + (T & 1) * (2 * TILE_E);
        const unsigned short* Bb = Ab + TILE_E;
        unsigned short* An = (unsigned short*)sh + ((T & 1) ^ 1) * (2 * TILE_E);
        unsigned short* Bn = An + TILE_E;
        bool pf = (T < NKT - 1);
        int kn = T + 1;

        bf16x8 af[2][2], bp[4][2];

        // ---- ph0: 12 reads (af q0 + all bp); stage next B (4 loads) ----
#pragma unroll
        for (int i = 0; i < 2; ++i) { af[i][0] = LDA(Ab, i, sl0); af[i][1] = LDA(Ab, i, sl1); }
#pragma unroll
        for (int n = 0; n < 4; ++n) { bp[n][0] = LDB(Bb, n, sl0); bp[n][1] = LDB(Bb, n, sl1); }
        if (pf) { stageB(Bn, 0, kn); stageB(Bn, 1, kn); stageB(Bn, 2, kn); stageB(Bn, 3, kn); }
        BARRIER();
        MFMA_Q(0);
        BARRIER();

        // ---- ph1: af q1; stage next A rows 0-127 ----
#pragma unroll
        for (int i = 0; i < 2; ++i) { af[i][0] = LDA(Ab, 2 + i, sl0); af[i][1] = LDA(Ab, 2 + i, sl1); }
        if (pf) { stageA(An, 0, kn); stageA(An, 1, kn); }
        BARRIER();
        MFMA_Q(1);
        BARRIER();

        // ---- ph2: af q2; stage next A rows 128-255 ----
#pragma unroll
        for (int i = 0; i < 2; ++i) { af[i][0] = LDA(Ab, 4 + i, sl0); af[i][1] = LDA(Ab, 4 + i, sl1); }
        if (pf) { stageA(An, 2, kn); stageA(An, 3, kn); }
        BARRIER();
        MFMA_Q(2);
        BARRIER();

        // ---- ph3: af q3; MFMA; drain staging (youngest ~1.5 phases old) ----
#pragma unroll
        for (int i = 0; i < 2; ++i) { af[i][0] = LDA(Ab, 6 + i, sl0); af[i][1] = LDA(Ab, 6 + i, sl1); }
        BARRIER();
        MFMA_Q(3);
        WAITVM(0);
        BARRIER();
    }

    // Epilogue: C/D map col=lane&15, row=(lane>>4)*4+reg; fused hardtanh
#pragma unroll
    for (int m = 0; m < 8; ++m) {
#pragma unroll
        for (int n = 0; n < 4; ++n) {
#pragma unroll
            for (int r = 0; r < 4; ++r) {
                int row = m0 + wm * 128 + m * 16 + lg * 4 + r;
                int col = n0 + wn * 64 + n * 16 + lrow;
                float v = acc[m][n][r];
                v = fminf(fmaxf(v, -1.0f), 1.0f);
                out[(size_t)row * OUT_DIM + col] = v;
            }
        }
    }
}

extern "C" void kernel_launch(void* const* d_in, const int* in_sizes, int n_in,
                              void* d_out, int out_size, void* d_ws, size_t ws_size,
                              hipStream_t stream) {
    const float* x = (const float*)d_in[0];
    const float* w = (const float*)d_in[1];
    const float* gamma = (const float*)d_in[2];
    const float* beta = (const float*)d_in[3];
    float* out = (float*)d_out;

    float* wsf = (float*)d_ws;
    float* psum = wsf;                                   // 32*2048 f32
    float* psq = wsf + 32 * IN_DIM;                      // 32*2048 f32
    float* scale = wsf + 64 * IN_DIM;                    // 2048 f32
    float* shift = wsf + 65 * IN_DIM;                    // 2048 f32
    unsigned short* Bsgn = (unsigned short*)(wsf + 66 * IN_DIM);  // 8 MB
    unsigned short* Acat = Bsgn + (size_t)OUT_DIM * IN_DIM;       // 64 MB

    k_stats<<<dim3(8, 32), 256, 0, stream>>>(x, psum, psq);
    k_finalize<<<8, 256, 0, stream>>>(psum, psq, gamma, beta, scale, shift);
    k_prep_a<<<B_DIM, 256, 0, stream>>>(x, scale, shift, Acat);
    k_prep_b<<<OUT_DIM, 256, 0, stream>>>(w, Bsgn);
    k_gemm<<<NWG, 512, 0, stream>>>(Acat, Bsgn, out);
}

// Round 12
// 135.806 us; speedup vs baseline: 2.5043x; 1.2245x over previous
//
#include <hip/hip_runtime.h>
#include <hip/hip_bf16.h>

#define B_DIM 8192
#define IN_DIM 2048
#define OUT_DIM 2048

typedef __attribute__((ext_vector_type(4))) int i32x4;

// ---------------- Stage 1: per-column sum/sumsq/min/max (deterministic) --------
__global__ void k_stats(const float* __restrict__ x, float* __restrict__ psum,
                        float* __restrict__ psq, float* __restrict__ pmn,
                        float* __restrict__ pmx) {
    int col = blockIdx.x * 256 + threadIdx.x;
    int chunk = blockIdx.y;
    const float* p = x + (size_t)chunk * 256 * IN_DIM + col;
    float s = 0.f, s2 = 0.f, mn = 3.0e38f, mx = -3.0e38f;
#pragma unroll 8
    for (int r = 0; r < 256; ++r) {
        float v = p[(size_t)r * IN_DIM];
        s += v;
        s2 = fmaf(v, v, s2);
        mn = fminf(mn, v);
        mx = fmaxf(mx, v);
    }
    psum[chunk * IN_DIM + col] = s;
    psq[chunk * IN_DIM + col] = s2;
    pmn[chunk * IN_DIM + col] = mn;
    pmx[chunk * IN_DIM + col] = mx;
}

// ---------------- Stage 2: finalize mean/var -> scale/shift + |xn| bound -------
__global__ void k_finalize(const float* __restrict__ psum, const float* __restrict__ psq,
                           const float* __restrict__ pmn, const float* __restrict__ pmx,
                           const float* __restrict__ gamma, const float* __restrict__ beta,
                           float* __restrict__ scale, float* __restrict__ shift,
                           float* __restrict__ bcol) {
    int c = blockIdx.x * 256 + threadIdx.x;
    float s = 0.f, s2 = 0.f, mn = 3.0e38f, mx = -3.0e38f;
#pragma unroll
    for (int ch = 0; ch < 32; ++ch) {
        s += psum[ch * IN_DIM + c];
        s2 += psq[ch * IN_DIM + c];
        mn = fminf(mn, pmn[ch * IN_DIM + c]);
        mx = fmaxf(mx, pmx[ch * IN_DIM + c]);
    }
    float mean = s * (1.0f / B_DIM);
    float var = fmaf(-mean, mean, s2 * (1.0f / B_DIM));
    float sc = gamma[c] * rsqrtf(var + 1e-5f);
    float bt = fmaf(-mean, sc, beta[c]);
    scale[c] = sc;
    shift[c] = bt;
    bcol[c] = fmaxf(fabsf(fmaf(mn, sc, bt)), fabsf(fmaf(mx, sc, bt)));
}

// ---------------- Stage 2b: global max -> quant scales -------------------------
__global__ void k_scale(const float* __restrict__ bcol, float* __restrict__ sbuf) {
    __shared__ float red[4];
    int t = threadIdx.x;
    float m = 0.f;
#pragma unroll
    for (int i = 0; i < 8; ++i) m = fmaxf(m, bcol[t * 8 + i]);
#pragma unroll
    for (int off = 32; off; off >>= 1) m = fmaxf(m, __shfl_xor(m, off));
    if ((t & 63) == 0) red[t >> 6] = m;
    __syncthreads();
    if (t == 0) {
        float M = fmaxf(fmaxf(red[0], red[1]), fmaxf(red[2], red[3]));
        float s = M * (1.0f / 127.0f);
        sbuf[0] = s * (1.0f / 254.0f);  // s_lo: y = s_lo * (254*S_hi + S_lo)
        sbuf[1] = 127.0f / M;           // 1/s
    }
}

// ---------------- Stage 3: xn -> i8 dual-slice hi|lo [8192][4096] --------------
__global__ void k_prep_a(const float* __restrict__ x, const float* __restrict__ scale,
                         const float* __restrict__ shift, const float* __restrict__ sbuf,
                         unsigned char* __restrict__ Ai) {
    int row = blockIdx.x;
    int c0 = threadIdx.x * 8;
    float inv_s = sbuf[1];
    const float4* px = (const float4*)(x + (size_t)row * IN_DIM + c0);
    float4 v0 = px[0], v1 = px[1];
    const float4* ps = (const float4*)(scale + c0);
    float4 s0 = ps[0], s1 = ps[1];
    const float4* pb = (const float4*)(shift + c0);
    float4 b0 = pb[0], b1 = pb[1];
    float xs[8] = {v0.x, v0.y, v0.z, v0.w, v1.x, v1.y, v1.z, v1.w};
    float ss[8] = {s0.x, s0.y, s0.z, s0.w, s1.x, s1.y, s1.z, s1.w};
    float bb[8] = {b0.x, b0.y, b0.z, b0.w, b1.x, b1.y, b1.z, b1.w};
    union { unsigned char u[8]; uint2 v; } hb, lb;
#pragma unroll
    for (int j = 0; j < 8; ++j) {
        float xn = fmaf(xs[j], ss[j], bb[j]);
        float tq = xn * inv_s;              // |tq| <= 127 by construction
        float qh = rintf(tq);
        int ih = (int)qh;
        int il = (int)rintf((tq - qh) * 254.0f);  // |.| <= 127
        hb.u[j] = (unsigned char)ih;
        lb.u[j] = (unsigned char)il;
    }
    size_t base = (size_t)row * 4096 + c0;
    *(uint2*)(Ai + base) = hb.v;
    *(uint2*)(Ai + base + 2048) = lb.v;
}

// ---------------- Stage 4: weight sign -> i8 +-1 [2048][2048] ------------------
__global__ void k_prep_b(const float* __restrict__ w, unsigned char* __restrict__ Bi) {
    int row = blockIdx.x;
    int c0 = threadIdx.x * 8;
    const float4* pw = (const float4*)(w + (size_t)row * IN_DIM + c0);
    float4 v0 = pw[0], v1 = pw[1];
    float wv[8] = {v0.x, v0.y, v0.z, v0.w, v1.x, v1.y, v1.z, v1.w};
    union { unsigned char u[8]; uint2 v; } sb;
#pragma unroll
    for (int j = 0; j < 8; ++j) sb.u[j] = (wv[j] >= 0.0f) ? 0x01u : 0xFFu;
    *(uint2*)(Bi + (size_t)row * IN_DIM + c0) = sb.v;
}

// ---------------- Stage 5: R5 skeleton, i8 16x16x64 MFMA, NKT=32 ---------------
// Byte geometry of a [256][128]B i8 tile == bf16 [256][64] tile: identical
// slots, swizzle, staging. Hi tiles 0-15, lo 16-31; exact fixup acc*=254
// between; y = s_lo * S. B k-index = (kt&15)*128 (weights repeat per slice).
#define BM 256
#define BN 256
#define NWG ((B_DIM / BM) * (OUT_DIM / BN))  // 256
#define NKT 32
#define TILE_B 32768                          // 256 rows x 128 B

#define MEMF() asm volatile("" ::: "memory")
#define BARRIER() do { MEMF(); __builtin_amdgcn_s_barrier(); MEMF(); } while (0)
#define WAITVM(N) asm volatile("s_waitcnt vmcnt(" #N ")" ::: "memory")
#define WAITLGKM0() asm volatile("s_waitcnt lgkmcnt(0)" ::: "memory")

__device__ __forceinline__ void gload16(const void* g, void* l) {
    __builtin_amdgcn_global_load_lds(
        (const __attribute__((address_space(1))) void*)g,
        (__attribute__((address_space(3))) void*)l,
        16, 0, 0);
}

__global__ __launch_bounds__(512, 2) void k_gemm(const unsigned char* __restrict__ A,
                                                 const unsigned char* __restrict__ Bs,
                                                 const float* __restrict__ sbuf,
                                                 float* __restrict__ out) {
    __shared__ __align__(16) unsigned char sh[4 * TILE_B];  // 128 KiB

    int bid = blockIdx.x;
    int swz = (bid & 7) * (NWG / 8) + (bid >> 3);
    int mt = swz >> 3, nt = swz & 7;
    int m0 = mt * BM, n0 = nt * BN;

    int t = threadIdx.x;
    int lane = t & 63, w = t >> 6;
    int wm = w >> 1, wn = w & 1;         // 4m x 2n waves; per-wave out 64 x 128
    int lrow = lane & 15, lg = lane >> 4;
    int lq = lane >> 3, lslot = lane & 7;
    int tsl = lslot ^ lq;

    int sl0 = (lg ^ (lane & 7)) << 4;          // ks=0 slot byte offset
    int sl1 = ((lg + 4) ^ (lane & 7)) << 4;    // ks=1

    int aRd = (wm * 64 + lrow) * 128;
    int bRd = (wn * 128 + lrow) * 128;

    auto stageA = [&](unsigned char* abuf, int j, int kt) {
        int q = wn * 4 + j;
        const unsigned char* src =
            A + (size_t)(m0 + wm * 64 + q * 8 + lq) * 4096 + kt * 128 + tsl * 16;
        gload16(src, abuf + wm * 8192 + q * 1024 + lane * 16);
    };
    auto stageB = [&](unsigned char* bbuf, int i, int j, int kt) {
        int cb = 2 * wn + i;
        int q = wm * 2 + j;
        const unsigned char* src =
            Bs + (size_t)(n0 + cb * 64 + q * 8 + lq) * 2048 + (kt & 15) * 128 + tsl * 16;
        gload16(src, bbuf + cb * 8192 + q * 1024 + lane * 16);
    };

    i32x4 acc[4][8] = {};

#define LDA(buf, m, sl) (*(const i32x4*)&(buf)[aRd + (m) * 2048 + (sl)])
#define LDB(buf, n, sl) (*(const i32x4*)&(buf)[bRd + (n) * 2048 + (sl)])
#define MFMA_PAIR(NP, BP)                                                          \
    do {                                                                           \
        __builtin_amdgcn_s_setprio(1);                                             \
        _Pragma("unroll") for (int ks = 0; ks < 2; ++ks)                           \
            _Pragma("unroll") for (int m = 0; m < 4; ++m)                          \
                _Pragma("unroll") for (int i = 0; i < 2; ++i)                      \
                    acc[m][(NP) + i] = __builtin_amdgcn_mfma_i32_16x16x64_i8(      \
                        af[m][ks], BP[i][ks], acc[m][(NP) + i], 0, 0, 0);          \
        __builtin_amdgcn_s_setprio(0);                                             \
    } while (0)

    i32x4 af[4][2];
    i32x4 bpA[2][2], bpB[2][2], bpC[2][2], bpD[2][2];

    // Prologue (R5 verbatim): stage tile0 A + B chunk0; drain; issue B chunk1.
    {
        unsigned char* A0b = sh;
        unsigned char* B0b = sh + TILE_B;
        stageA(A0b, 0, 0); stageA(A0b, 1, 0); stageB(B0b, 0, 0, 0);
        stageB(B0b, 0, 1, 0); stageA(A0b, 2, 0); stageA(A0b, 3, 0);
        WAITVM(0);
        BARRIER();
        stageB(B0b, 1, 0, 0); stageB(B0b, 1, 1, 0);
#pragma unroll
        for (int m = 0; m < 4; ++m) { af[m][0] = LDA(A0b, m, sl0); af[m][1] = LDA(A0b, m, sl1); }
#pragma unroll
        for (int i = 0; i < 2; ++i) { bpA[i][0] = LDB(B0b, i, sl0); bpA[i][1] = LDB(B0b, i, sl1); }
    }

#define TILE_BODY(T, PF)                                                               \
    do {                                                                               \
        const unsigned char* Ab = sh + ((T) & 1) * (2 * TILE_B);                       \
        const unsigned char* Bb = Ab + TILE_B;                                         \
        unsigned char* An = sh + (((T) & 1) ^ 1) * (2 * TILE_B);                       \
        unsigned char* Bn = An + TILE_B;                                               \
        bool pf = (PF);                                                                \
        int kn = (T) + 1;                                                              \
        if (pf) { stageA(An, 0, kn); stageA(An, 1, kn); stageB(Bn, 0, 0, kn); }        \
        _Pragma("unroll") for (int i = 0; i < 2; ++i) {                                \
            bpB[i][0] = LDB(Bb, 2 + i, sl0); bpB[i][1] = LDB(Bb, 2 + i, sl1); }        \
        MFMA_PAIR(0, bpA);                                                             \
        if (pf) { WAITVM(3); } else { WAITVM(0); }                                     \
        WAITLGKM0();                                                                   \
        BARRIER();                                                                     \
        if (pf) { stageB(Bn, 0, 1, kn); stageA(An, 2, kn); stageA(An, 3, kn); }        \
        _Pragma("unroll") for (int i = 0; i < 2; ++i) {                                \
            bpC[i][0] = LDB(Bb, 4 + i, sl0); bpC[i][1] = LDB(Bb, 4 + i, sl1); }        \
        MFMA_PAIR(2, bpB);                                                             \
        _Pragma("unroll") for (int i = 0; i < 2; ++i) {                                \
            bpD[i][0] = LDB(Bb, 6 + i, sl0); bpD[i][1] = LDB(Bb, 6 + i, sl1); }        \
        MFMA_PAIR(4, bpC);                                                             \
        WAITVM(0);                                                                     \
        WAITLGKM0();                                                                   \
        BARRIER();                                                                     \
        if (pf) { stageB(Bn, 1, 0, kn); stageB(Bn, 1, 1, kn); }                        \
        MFMA_PAIR(6, bpD);                                                             \
        if (pf) {                                                                      \
            _Pragma("unroll") for (int m = 0; m < 4; ++m) {                            \
                af[m][0] = LDA(An, m, sl0); af[m][1] = LDA(An, m, sl1); }              \
            _Pragma("unroll") for (int i = 0; i < 2; ++i) {                            \
                bpA[i][0] = LDB(Bn, i, sl0); bpA[i][1] = LDB(Bn, i, sl1); }            \
        }                                                                              \
    } while (0)

#pragma unroll 2
    for (int T = 0; T < 16; ++T) TILE_BODY(T, true);

    // Exact fixup: S := 254*S_hi before accumulating the lo slice (fits i32).
#pragma unroll
    for (int m = 0; m < 4; ++m)
#pragma unroll
        for (int n = 0; n < 8; ++n) acc[m][n] = acc[m][n] * 254;

#pragma unroll 2
    for (int T = 16; T < NKT; ++T) TILE_BODY(T, T < NKT - 1);

    // Epilogue: y = s_lo * S, hardtanh; C/D map col=lane&15, row=(lane>>4)*4+reg
    float s_lo = sbuf[0];
#pragma unroll
    for (int m = 0; m < 4; ++m) {
#pragma unroll
        for (int n = 0; n < 8; ++n) {
#pragma unroll
            for (int r = 0; r < 4; ++r) {
                int row = m0 + wm * 64 + m * 16 + lg * 4 + r;
                int col = n0 + wn * 128 + n * 16 + lrow;
                float v = (float)acc[m][n][r] * s_lo;
                v = fminf(fmaxf(v, -1.0f), 1.0f);
                out[(size_t)row * OUT_DIM + col] = v;
            }
        }
    }
}

extern "C" void kernel_launch(void* const* d_in, const int* in_sizes, int n_in,
                              void* d_out, int out_size, void* d_ws, size_t ws_size,
                              hipStream_t stream) {
    const float* x = (const float*)d_in[0];
    const float* w = (const float*)d_in[1];
    const float* gamma = (const float*)d_in[2];
    const float* beta = (const float*)d_in[3];
    float* out = (float*)d_out;

    float* wsf = (float*)d_ws;
    float* psum = wsf;                        // 32*2048
    float* psq = wsf + 65536;                 // 32*2048
    float* pmn = wsf + 131072;                // 32*2048
    float* pmx = wsf + 196608;                // 32*2048
    float* scale = wsf + 262144;              // 2048
    float* shift = wsf + 264192;              // 2048
    float* bcol = wsf + 266240;               // 2048
    float* sbuf = wsf + 268288;               // 16
    unsigned char* Bi = (unsigned char*)(wsf + 270336);        // 4 MB
    unsigned char* Ai = Bi + (size_t)OUT_DIM * IN_DIM;         // 32 MB

    k_stats<<<dim3(8, 32), 256, 0, stream>>>(x, psum, psq, pmn, pmx);
    k_finalize<<<8, 256, 0, stream>>>(psum, psq, pmn, pmx, gamma, beta, scale, shift, bcol);
    k_scale<<<1, 256, 0, stream>>>(bcol, sbuf);
    k_prep_a<<<B_DIM, 256, 0, stream>>>(x, scale, shift, sbuf, Ai);
    k_prep_b<<<OUT_DIM, 256, 0, stream>>>(w, Bi);
    k_gemm<<<NWG, 512, 0, stream>>>(Ai, Bi, sbuf, out);
}

// Round 13
// 113.276 us; speedup vs baseline: 3.0023x; 1.1989x over previous
//
#include <hip/hip_runtime.h>
#include <hip/hip_bf16.h>

#define B_DIM 8192
#define IN_DIM 2048
#define OUT_DIM 2048
#define NCH 128   // row-chunks for stats (64 rows each)

typedef __attribute__((ext_vector_type(4))) int i32x4;

// ---------------- Stage 1: per-column sum/sumsq/min/max (deterministic) --------
__global__ void k_stats(const float* __restrict__ x, float* __restrict__ psum,
                        float* __restrict__ psq, float* __restrict__ pmn,
                        float* __restrict__ pmx) {
    int col = blockIdx.x * 256 + threadIdx.x;
    int chunk = blockIdx.y;                       // 128 chunks x 64 rows
    const float* p = x + (size_t)chunk * 64 * IN_DIM + col;
    float s = 0.f, s2 = 0.f, mn = 3.0e38f, mx = -3.0e38f;
#pragma unroll 8
    for (int r = 0; r < 64; ++r) {
        float v = p[(size_t)r * IN_DIM];
        s += v;
        s2 = fmaf(v, v, s2);
        mn = fminf(mn, v);
        mx = fmaxf(mx, v);
    }
    psum[chunk * IN_DIM + col] = s;
    psq[chunk * IN_DIM + col] = s2;
    pmn[chunk * IN_DIM + col] = mn;
    pmx[chunk * IN_DIM + col] = mx;
}

// ---------------- Stage 2: finalize mean/var -> scale/shift + |xn| bound -------
__global__ void k_finalize(const float* __restrict__ psum, const float* __restrict__ psq,
                           const float* __restrict__ pmn, const float* __restrict__ pmx,
                           const float* __restrict__ gamma, const float* __restrict__ beta,
                           float* __restrict__ scale, float* __restrict__ shift,
                           float* __restrict__ bcol) {
    int c = blockIdx.x * 256 + threadIdx.x;
    float s = 0.f, s2 = 0.f, mn = 3.0e38f, mx = -3.0e38f;
#pragma unroll 8
    for (int ch = 0; ch < NCH; ++ch) {
        s += psum[ch * IN_DIM + c];
        s2 += psq[ch * IN_DIM + c];
        mn = fminf(mn, pmn[ch * IN_DIM + c]);
        mx = fmaxf(mx, pmx[ch * IN_DIM + c]);
    }
    float mean = s * (1.0f / B_DIM);
    float var = fmaf(-mean, mean, s2 * (1.0f / B_DIM));
    float sc = gamma[c] * rsqrtf(var + 1e-5f);
    float bt = fmaf(-mean, sc, beta[c]);
    scale[c] = sc;
    shift[c] = bt;
    bcol[c] = fmaxf(fabsf(fmaf(mn, sc, bt)), fabsf(fmaf(mx, sc, bt)));
}

// ---------------- Stage 2b: global max -> quant scales -------------------------
__global__ void k_scale(const float* __restrict__ bcol, float* __restrict__ sbuf) {
    __shared__ float red[4];
    int t = threadIdx.x;
    float m = 0.f;
#pragma unroll
    for (int i = 0; i < 8; ++i) m = fmaxf(m, bcol[t * 8 + i]);
#pragma unroll
    for (int off = 32; off; off >>= 1) m = fmaxf(m, __shfl_xor(m, off));
    if ((t & 63) == 0) red[t >> 6] = m;
    __syncthreads();
    if (t == 0) {
        float M = fmaxf(fmaxf(red[0], red[1]), fmaxf(red[2], red[3]));
        float s = M * (1.0f / 127.0f);
        sbuf[0] = s * (1.0f / 254.0f);  // s_lo: y = s_lo * (254*S_hi + S_lo)
        sbuf[1] = 127.0f / M;           // 1/s
    }
}

// ---------------- Stage 3: xn -> i8 dual-slice hi|lo [8192][4096] --------------
__global__ void k_prep_a(const float* __restrict__ x, const float* __restrict__ scale,
                         const float* __restrict__ shift, const float* __restrict__ sbuf,
                         unsigned char* __restrict__ Ai) {
    int row = blockIdx.x;
    int c0 = threadIdx.x * 8;
    float inv_s = sbuf[1];
    const float4* px = (const float4*)(x + (size_t)row * IN_DIM + c0);
    float4 v0 = px[0], v1 = px[1];
    const float4* ps = (const float4*)(scale + c0);
    float4 s0 = ps[0], s1 = ps[1];
    const float4* pb = (const float4*)(shift + c0);
    float4 b0 = pb[0], b1 = pb[1];
    float xs[8] = {v0.x, v0.y, v0.z, v0.w, v1.x, v1.y, v1.z, v1.w};
    float ss[8] = {s0.x, s0.y, s0.z, s0.w, s1.x, s1.y, s1.z, s1.w};
    float bb[8] = {b0.x, b0.y, b0.z, b0.w, b1.x, b1.y, b1.z, b1.w};
    union { unsigned char u[8]; uint2 v; } hb, lb;
#pragma unroll
    for (int j = 0; j < 8; ++j) {
        float xn = fmaf(xs[j], ss[j], bb[j]);
        float tq = xn * inv_s;              // |tq| <= 127 by construction
        float qh = rintf(tq);
        int ih = (int)qh;
        int il = (int)rintf((tq - qh) * 254.0f);  // |.| <= 127
        hb.u[j] = (unsigned char)ih;
        lb.u[j] = (unsigned char)il;
    }
    size_t base = (size_t)row * 4096 + c0;
    *(uint2*)(Ai + base) = hb.v;
    *(uint2*)(Ai + base + 2048) = lb.v;
}

// ---------------- Stage 4: weight sign -> i8 +-1 [2048][2048] ------------------
__global__ void k_prep_b(const float* __restrict__ w, unsigned char* __restrict__ Bi) {
    int row = blockIdx.x;
    int c0 = threadIdx.x * 8;
    const float4* pw = (const float4*)(w + (size_t)row * IN_DIM + c0);
    float4 v0 = pw[0], v1 = pw[1];
    float wv[8] = {v0.x, v0.y, v0.z, v0.w, v1.x, v1.y, v1.z, v1.w};
    union { unsigned char u[8]; uint2 v; } sb;
#pragma unroll
    for (int j = 0; j < 8; ++j) sb.u[j] = (wv[j] >= 0.0f) ? 0x01u : 0xFFu;
    *(uint2*)(Bi + (size_t)row * IN_DIM + c0) = sb.v;
}

// ---------------- Stage 5: R5 skeleton, i8 16x16x64 MFMA, NKT=32 ---------------
// Byte geometry of a [256][128]B i8 tile == bf16 [256][64] tile: identical
// slots, swizzle, staging. Hi tiles 0-15, lo 16-31; exact fixup acc*=254
// between; y = s_lo * S. B k-index = (kt&15)*128 (weights repeat per slice).
#define BM 256
#define BN 256
#define NWG ((B_DIM / BM) * (OUT_DIM / BN))  // 256
#define NKT 32
#define TILE_B 32768                          // 256 rows x 128 B

#define MEMF() asm volatile("" ::: "memory")
#define BARRIER() do { MEMF(); __builtin_amdgcn_s_barrier(); MEMF(); } while (0)
#define WAITVM(N) asm volatile("s_waitcnt vmcnt(" #N ")" ::: "memory")
#define WAITLGKM0() asm volatile("s_waitcnt lgkmcnt(0)" ::: "memory")

__device__ __forceinline__ void gload16(const void* g, void* l) {
    __builtin_amdgcn_global_load_lds(
        (const __attribute__((address_space(1))) void*)g,
        (__attribute__((address_space(3))) void*)l,
        16, 0, 0);
}

__global__ __launch_bounds__(512, 2) void k_gemm(const unsigned char* __restrict__ A,
                                                 const unsigned char* __restrict__ Bs,
                                                 const float* __restrict__ sbuf,
                                                 float* __restrict__ out) {
    __shared__ __align__(16) unsigned char sh[4 * TILE_B];  // 128 KiB

    int bid = blockIdx.x;
    int swz = (bid & 7) * (NWG / 8) + (bid >> 3);
    int mt = swz >> 3, nt = swz & 7;
    int m0 = mt * BM, n0 = nt * BN;

    int t = threadIdx.x;
    int lane = t & 63, w = t >> 6;
    int wm = w >> 1, wn = w & 1;         // 4m x 2n waves; per-wave out 64 x 128
    int lrow = lane & 15, lg = lane >> 4;
    int lq = lane >> 3, lslot = lane & 7;
    int tsl = lslot ^ lq;

    int sl0 = (lg ^ (lane & 7)) << 4;          // ks=0 slot byte offset
    int sl1 = ((lg + 4) ^ (lane & 7)) << 4;    // ks=1

    int aRd = (wm * 64 + lrow) * 128;
    int bRd = (wn * 128 + lrow) * 128;

    auto stageA = [&](unsigned char* abuf, int j, int kt) {
        int q = wn * 4 + j;
        const unsigned char* src =
            A + (size_t)(m0 + wm * 64 + q * 8 + lq) * 4096 + kt * 128 + tsl * 16;
        gload16(src, abuf + wm * 8192 + q * 1024 + lane * 16);
    };
    auto stageB = [&](unsigned char* bbuf, int i, int j, int kt) {
        int cb = 2 * wn + i;
        int q = wm * 2 + j;
        const unsigned char* src =
            Bs + (size_t)(n0 + cb * 64 + q * 8 + lq) * 2048 + (kt & 15) * 128 + tsl * 16;
        gload16(src, bbuf + cb * 8192 + q * 1024 + lane * 16);
    };

    i32x4 acc[4][8] = {};

#define LDA(buf, m, sl) (*(const i32x4*)&(buf)[aRd + (m) * 2048 + (sl)])
#define LDB(buf, n, sl) (*(const i32x4*)&(buf)[bRd + (n) * 2048 + (sl)])
#define MFMA_PAIR(NP, BP)                                                          \
    do {                                                                           \
        __builtin_amdgcn_s_setprio(1);                                             \
        _Pragma("unroll") for (int ks = 0; ks < 2; ++ks)                           \
            _Pragma("unroll") for (int m = 0; m < 4; ++m)                          \
                _Pragma("unroll") for (int i = 0; i < 2; ++i)                      \
                    acc[m][(NP) + i] = __builtin_amdgcn_mfma_i32_16x16x64_i8(      \
                        af[m][ks], BP[i][ks], acc[m][(NP) + i], 0, 0, 0);          \
        __builtin_amdgcn_s_setprio(0);                                             \
    } while (0)

    i32x4 af[4][2];
    i32x4 bpA[2][2], bpB[2][2], bpC[2][2], bpD[2][2];

    // Prologue (R5 verbatim): stage tile0 A + B chunk0; drain; issue B chunk1.
    {
        unsigned char* A0b = sh;
        unsigned char* B0b = sh + TILE_B;
        stageA(A0b, 0, 0); stageA(A0b, 1, 0); stageB(B0b, 0, 0, 0);
        stageB(B0b, 0, 1, 0); stageA(A0b, 2, 0); stageA(A0b, 3, 0);
        WAITVM(0);
        BARRIER();
        stageB(B0b, 1, 0, 0); stageB(B0b, 1, 1, 0);
#pragma unroll
        for (int m = 0; m < 4; ++m) { af[m][0] = LDA(A0b, m, sl0); af[m][1] = LDA(A0b, m, sl1); }
#pragma unroll
        for (int i = 0; i < 2; ++i) { bpA[i][0] = LDB(B0b, i, sl0); bpA[i][1] = LDB(B0b, i, sl1); }
    }

#define TILE_BODY(T, PF)                                                               \
    do {                                                                               \
        const unsigned char* Ab = sh + ((T) & 1) * (2 * TILE_B);                       \
        const unsigned char* Bb = Ab + TILE_B;                                         \
        unsigned char* An = sh + (((T) & 1) ^ 1) * (2 * TILE_B);                       \
        unsigned char* Bn = An + TILE_B;                                               \
        bool pf = (PF);                                                                \
        int kn = (T) + 1;                                                              \
        if (pf) { stageA(An, 0, kn); stageA(An, 1, kn); stageB(Bn, 0, 0, kn); }        \
        _Pragma("unroll") for (int i = 0; i < 2; ++i) {                                \
            bpB[i][0] = LDB(Bb, 2 + i, sl0); bpB[i][1] = LDB(Bb, 2 + i, sl1); }        \
        MFMA_PAIR(0, bpA);                                                             \
        if (pf) { WAITVM(3); } else { WAITVM(0); }                                     \
        WAITLGKM0();                                                                   \
        BARRIER();                                                                     \
        if (pf) { stageB(Bn, 0, 1, kn); stageA(An, 2, kn); stageA(An, 3, kn); }        \
        _Pragma("unroll") for (int i = 0; i < 2; ++i) {                                \
            bpC[i][0] = LDB(Bb, 4 + i, sl0); bpC[i][1] = LDB(Bb, 4 + i, sl1); }        \
        MFMA_PAIR(2, bpB);                                                             \
        _Pragma("unroll") for (int i = 0; i < 2; ++i) {                                \
            bpD[i][0] = LDB(Bb, 6 + i, sl0); bpD[i][1] = LDB(Bb, 6 + i, sl1); }        \
        MFMA_PAIR(4, bpC);                                                             \
        WAITVM(0);                                                                     \
        WAITLGKM0();                                                                   \
        BARRIER();                                                                     \
        if (pf) { stageB(Bn, 1, 0, kn); stageB(Bn, 1, 1, kn); }                        \
        MFMA_PAIR(6, bpD);                                                             \
        if (pf) {                                                                      \
            _Pragma("unroll") for (int m = 0; m < 4; ++m) {                            \
                af[m][0] = LDA(An, m, sl0); af[m][1] = LDA(An, m, sl1); }              \
            _Pragma("unroll") for (int i = 0; i < 2; ++i) {                            \
                bpA[i][0] = LDB(Bn, i, sl0); bpA[i][1] = LDB(Bn, i, sl1); }            \
        }                                                                              \
    } while (0)

#pragma unroll 2
    for (int T = 0; T < 16; ++T) TILE_BODY(T, true);

    // Exact fixup: S := 254*S_hi before accumulating the lo slice (fits i32).
#pragma unroll
    for (int m = 0; m < 4; ++m)
#pragma unroll
        for (int n = 0; n < 8; ++n) acc[m][n] = acc[m][n] * 254;

#pragma unroll 2
    for (int T = 16; T < NKT; ++T) TILE_BODY(T, T < NKT - 1);

    // Epilogue: y = s_lo * S, hardtanh; C/D map col=lane&15, row=(lane>>4)*4+reg
    float s_lo = sbuf[0];
#pragma unroll
    for (int m = 0; m < 4; ++m) {
#pragma unroll
        for (int n = 0; n < 8; ++n) {
#pragma unroll
            for (int r = 0; r < 4; ++r) {
                int row = m0 + wm * 64 + m * 16 + lg * 4 + r;
                int col = n0 + wn * 128 + n * 16 + lrow;
                float v = (float)acc[m][n][r] * s_lo;
                v = fminf(fmaxf(v, -1.0f), 1.0f);
                out[(size_t)row * OUT_DIM + col] = v;
            }
        }
    }
}

extern "C" void kernel_launch(void* const* d_in, const int* in_sizes, int n_in,
                              void* d_out, int out_size, void* d_ws, size_t ws_size,
                              hipStream_t stream) {
    const float* x = (const float*)d_in[0];
    const float* w = (const float*)d_in[1];
    const float* gamma = (const float*)d_in[2];
    const float* beta = (const float*)d_in[3];
    float* out = (float*)d_out;

    float* wsf = (float*)d_ws;
    float* psum = wsf;                                // NCH*2048 = 262144
    float* psq = wsf + 262144;
    float* pmn = wsf + 524288;
    float* pmx = wsf + 786432;
    float* scale = wsf + 1048576;                     // 2048
    float* shift = wsf + 1050624;                     // 2048
    float* bcol = wsf + 1052672;                      // 2048
    float* sbuf = wsf + 1054720;                      // 16
    unsigned char* Bi = (unsigned char*)(wsf + 1056768);       // 4 MB
    unsigned char* Ai = Bi + (size_t)OUT_DIM * IN_DIM;         // 32 MB

    k_stats<<<dim3(8, NCH), 256, 0, stream>>>(x, psum, psq, pmn, pmx);
    k_finalize<<<8, 256, 0, stream>>>(psum, psq, pmn, pmx, gamma, beta, scale, shift, bcol);
    k_scale<<<1, 256, 0, stream>>>(bcol, sbuf);
    k_prep_a<<<B_DIM, 256, 0, stream>>>(x, scale, shift, sbuf, Ai);
    k_prep_b<<<OUT_DIM, 256, 0, stream>>>(w, Bi);
    k_gemm<<<NWG, 512, 0, stream>>>(Ai, Bi, sbuf, out);
}